// Round 3
// baseline (126.195 us; speedup 1.0000x reference)
//
#include <hip/hip_runtime.h>

typedef float f32x4 __attribute__((ext_vector_type(4)));
typedef short s16x8 __attribute__((ext_vector_type(8)));
typedef short s16x4 __attribute__((ext_vector_type(4)));
typedef unsigned short u16;

#define NB 8
#define NC 64
#define NN 4096
#define NK 8

__device__ __forceinline__ u16 f2bf_rne(float f) {
    unsigned u = __float_as_uint(f);
    u += 0x7FFFu + ((u >> 16) & 1u);
    return (u16)(u >> 16);
}
__device__ __forceinline__ u16 f2bf_trunc(float f) {
    return (u16)(__float_as_uint(f) >> 16);
}
__device__ __forceinline__ float bf2f(u16 v) {
    return __uint_as_float(((unsigned)v) << 16);
}

// ---------------------------------------------------------------------------
// Kernel 1: W' = [Wh(64); Wf(8); Wg(8)] (80x64) @ x[b] via MFMA.
// v3: weights staged to LDS with COALESCED loads (the old per-lane scattered
// weight gather was the suspected 40+ us pathology), frags built from LDS
// with stride-72 (conflict-spread) rows. x loads issued first to overlap.
// ---------------------------------------------------------------------------
__global__ __launch_bounds__(256, 4)
void precompute_qgh(const float* __restrict__ x,
                    const float* __restrict__ Wf,
                    const float* __restrict__ Wg,
                    const float* __restrict__ Wh,
                    u16* __restrict__ Qw, u16* __restrict__ Gw,
                    u16* __restrict__ Hw)
{
    const int b  = blockIdx.y;
    const int n0 = blockIdx.x * 64;
    const int t  = threadIdx.x;
    const int wave = t >> 6, lane = t & 63, col = lane & 15, quad = lane >> 4;
    const int n = n0 + wave * 16 + col;
    const float* xb = x + (size_t)b * NC * NN;

    __shared__ u16 Wl[80][72];   // rows 0..63 = Wh, 64..71 = Wf, 72..79 = Wg

    // issue x loads early (coalesced: 16 lanes x 4B = 64B segments)
    float xv[16];
    #pragma unroll
    for (int s = 0; s < 2; s++)
        #pragma unroll
        for (int kk = 0; kk < 8; kk++)
            xv[s * 8 + kk] = xb[(size_t)(s * 32 + quad * 8 + kk) * NN + n];

    // stage weights: each 64-lane wave handles one full row per iter (uniform
    // branch, fully coalesced 256B row loads)
    #pragma unroll
    for (int u = 0; u < 20; u++) {
        int v = t + u * 256, row = v >> 6, c = v & 63;
        float w = (row < 64) ? Wh[row * 64 + c]
                : (row < 72) ? Wf[(row - 64) * 64 + c]
                             : Wg[(row - 72) * 64 + c];
        Wl[row][c] = f2bf_rne(w);
    }
    __syncthreads();

    // B-frags from prefetched x
    s16x8 bfrag[2];
    #pragma unroll
    for (int s = 0; s < 2; s++)
        #pragma unroll
        for (int kk = 0; kk < 8; kk++)
            ((u16*)&bfrag[s])[kk] = f2bf_rne(xv[s * 8 + kk]);

    // A-frags from LDS (b128 reads, stride-72 rows spread banks)
    f32x4 d[5];
    #pragma unroll
    for (int mt = 0; mt < 5; mt++) d[mt] = (f32x4){0.f, 0.f, 0.f, 0.f};
    #pragma unroll
    for (int s = 0; s < 2; s++) {
        #pragma unroll
        for (int mt = 0; mt < 5; mt++) {
            int row = (mt < 4) ? mt * 16 + col : 64 + col;   // 64+col: Wf(0..7)|Wg(8..15)
            s16x8 af = *(const s16x8*)(&Wl[row][s * 32 + quad * 8]);
            d[mt] = __builtin_amdgcn_mfma_f32_16x16x32_bf16(af, bfrag[s], d[mt], 0, 0, 0);
        }
    }

    u16* Hb = Hw + (size_t)b * NC * NN;
    #pragma unroll
    for (int mt = 0; mt < 4; mt++)
        #pragma unroll
        for (int r = 0; r < 4; r++)
            Hb[(size_t)(mt * 16 + quad * 4 + r) * NN + n] = f2bf_rne(d[mt][r]);
    #pragma unroll
    for (int r = 0; r < 4; r++) {
        int m = quad * 4 + r;
        u16 v = f2bf_rne(d[4][r]);
        if (m < 8) Qw[((size_t)b * NN + n) * NK + m]       = v;
        else       Gw[((size_t)b * NN + n) * NK + (m - 8)] = v;
    }
}

// ---------------------------------------------------------------------------
// Kernel 2: flash attention over a j-partition. v3: double-buffered Vlds ->
// ONE barrier per chunk; S/exp/P phase (regs + per-wave LDS) overlaps other
// waves' V staging. Row sums via ones-B-frag MFMA.
// ---------------------------------------------------------------------------
__global__ __launch_bounds__(256, 4)
void attention_fa(const u16* __restrict__ Qw, const u16* __restrict__ Gw,
                  const u16* __restrict__ Hw,
                  u16* __restrict__ Opart, float* __restrict__ Lpart,
                  int jspan)
{
    const int b    = blockIdx.y;
    const int i0   = blockIdx.x * 64;
    const int part = blockIdx.z;
    const int t    = threadIdx.x;
    const int wave = t >> 6, lane = t & 63, col = lane & 15, quad = lane >> 4;

    __shared__ u16 Vlds[2][64][72];
    __shared__ u16 Plds[4][16][72];

    const u16* Qb = Qw + (size_t)b * NN * NK;
    const u16* Gb = Gw + (size_t)b * NN * NK;
    const u16* Hb = Hw + (size_t)b * NC * NN;

    s16x8 qfrag = *(const s16x8*)(Qb + (size_t)(i0 + wave * 16 + col) * NK);
    if (quad != 0) {
        #pragma unroll
        for (int i = 0; i < 8; i++) ((u16*)&qfrag)[i] = 0;
    }
    s16x8 ones;
    #pragma unroll
    for (int i = 0; i < 8; i++) ((u16*)&ones)[i] = 0x3F80;

    f32x4 oacc[4];
    #pragma unroll
    for (int ct = 0; ct < 4; ct++) oacc[ct] = (f32x4){0.f, 0.f, 0.f, 0.f};
    f32x4 lacc = (f32x4){0.f, 0.f, 0.f, 0.f};

    const int jbase  = part * jspan;
    const int chunks = jspan / 64;
    const int vc = t >> 3, vseg = t & 7;

    s16x8 vreg[2];
    #pragma unroll
    for (int u = 0; u < 2; u++)
        vreg[u] = *(const s16x8*)(Hb + (size_t)(u * 32 + vc) * NN + jbase + vseg * 8);

    for (int cc = 0; cc < chunks; cc++) {
        const int j0  = jbase + cc * 64;
        const int buf = cc & 1;

        // stage V for THIS chunk into buffer buf (last read 2 chunks ago)
        #pragma unroll
        for (int u = 0; u < 2; u++)
            *(s16x8*)(&Vlds[buf][u * 32 + vc][vseg * 8]) = vreg[u];

        // G frags + next-V prefetch (global, overlap with S phase)
        s16x8 gf[4];
        #pragma unroll
        for (int jt = 0; jt < 4; jt++)
            gf[jt] = *(const s16x8*)(Gb + (size_t)(j0 + jt * 16 + col) * NK);
        s16x8 vnext[2];
        #pragma unroll
        for (int u = 0; u < 2; u++)
            vnext[u] = *(const s16x8*)(Hb + (size_t)(u * 32 + vc) * NN + j0 + 64 + vseg * 8);

        // S = QK^T -> exp -> P (per-wave private LDS region)
        #pragma unroll
        for (int jt = 0; jt < 4; jt++) {
            f32x4 s = __builtin_amdgcn_mfma_f32_16x16x32_bf16(
                qfrag, gf[jt], (f32x4){0.f, 0.f, 0.f, 0.f}, 0, 0, 0);
            #pragma unroll
            for (int r = 0; r < 4; r++)
                Plds[wave][quad * 4 + r][jt * 16 + col] = f2bf_trunc(__expf(s[r]));
        }

        __syncthreads();   // single barrier: V[buf] writes visible everywhere

        // PV + row-sum MFMAs
        #pragma unroll
        for (int s2 = 0; s2 < 2; s2++) {
            s16x8 af = *(const s16x8*)(&Plds[wave][col][s2 * 32 + quad * 8]);
            lacc = __builtin_amdgcn_mfma_f32_16x16x32_bf16(af, ones, lacc, 0, 0, 0);
            #pragma unroll
            for (int ct = 0; ct < 4; ct++) {
                s16x8 bf = *(const s16x8*)(&Vlds[buf][ct * 16 + col][s2 * 32 + quad * 8]);
                oacc[ct] = __builtin_amdgcn_mfma_f32_16x16x32_bf16(af, bf, oacc[ct], 0, 0, 0);
            }
        }
        vreg[0] = vnext[0]; vreg[1] = vnext[1];
    }

    float* Lb = Lpart + ((size_t)part * NB + b) * NN + i0;
    if (col == 0) {
        #pragma unroll
        for (int r = 0; r < 4; r++) Lb[wave * 16 + quad * 4 + r] = lacc[r];
    }

    // transpose O to [c][i] through LDS (reuse Plds), coalesced store
    __syncthreads();
    u16 (*OT)[72] = (u16(*)[72])Plds;
    #pragma unroll
    for (int ct = 0; ct < 4; ct++)
        #pragma unroll
        for (int r = 0; r < 4; r++)
            OT[ct * 16 + col][wave * 16 + quad * 4 + r] = f2bf_rne(oacc[ct][r]);
    __syncthreads();

    u16* Ob = Opart + ((size_t)part * NB + b) * NC * NN;
    #pragma unroll
    for (int u = 0; u < 2; u++) {
        int c = u * 32 + vc;
        *(s16x8*)(Ob + (size_t)c * NN + i0 + vseg * 8) = *(const s16x8*)(&OT[c][vseg * 8]);
    }
}

// ---------------------------------------------------------------------------
// Kernel 3: out[b,c,i] = gamma * (sum_p O_p[b,c,i]) / (sum_p l_p[b,i]) + x
// ---------------------------------------------------------------------------
__global__ __launch_bounds__(256, 4)
void reduce_out(const u16* __restrict__ Opart, const float* __restrict__ Lpart,
                const float* __restrict__ x, const float* __restrict__ gamma,
                float* __restrict__ out, int parts)
{
    const int tid  = blockIdx.x * 256 + threadIdx.x;
    const int base = tid * 4;
    const int bc   = base >> 12;
    const int b    = bc >> 6;
    const int ii   = base & (NN - 1);

    float s[4] = {0.f, 0.f, 0.f, 0.f};
    float l[4] = {0.f, 0.f, 0.f, 0.f};
    for (int p = 0; p < parts; p++) {
        s16x4 ov = *(const s16x4*)(Opart + ((size_t)p * NB * NC + bc) * NN + ii);
        f32x4 lv = *(const f32x4*)(Lpart + ((size_t)p * NB + b) * NN + ii);
        #pragma unroll
        for (int e = 0; e < 4; e++) {
            s[e] += bf2f((u16)ov[e]);
            l[e] += lv[e];
        }
    }
    const float g = gamma[0];
    const f32x4 xv = *(const f32x4*)(x + base);
    f32x4 o;
    #pragma unroll
    for (int e = 0; e < 4; e++) o[e] = g * (s[e] / l[e]) + xv[e];
    *(f32x4*)(out + base) = o;
}

extern "C" void kernel_launch(void* const* d_in, const int* in_sizes, int n_in,
                              void* d_out, int out_size, void* d_ws, size_t ws_size,
                              hipStream_t stream) {
    const float* x     = (const float*)d_in[0];
    const float* Wf    = (const float*)d_in[1];
    const float* Wg    = (const float*)d_in[2];
    const float* Wh    = (const float*)d_in[3];
    const float* gamma = (const float*)d_in[4];
    float* out = (float*)d_out;

    u16* Qw = (u16*)d_ws;                       // [B][N][8]
    u16* Gw = Qw + (size_t)NB * NN * NK;        // [B][N][8]
    u16* Hw = Gw + (size_t)NB * NN * NK;        // [B][C][N]
    u16* Opart = Hw + (size_t)NB * NC * NN;     // [parts][B][C][N] bf16

    const size_t fixed = (size_t)(2 * NB * NN * NK + NB * NC * NN) * 2;
    int parts = 4;
    while (parts > 1) {
        size_t need = fixed + (size_t)parts * NB * NC * NN * 2
                            + (size_t)parts * NB * NN * 4 + 8192;
        if (need <= ws_size) break;
        parts >>= 1;
    }
    float* Lpart = (float*)(Opart + (size_t)parts * NB * NC * NN);
    const int jspan = NN / parts;

    precompute_qgh<<<dim3(64, NB), 256, 0, stream>>>(x, Wf, Wg, Wh, Qw, Gw, Hw);
    attention_fa<<<dim3(64, NB, parts), 256, 0, stream>>>(Qw, Gw, Hw, Opart, Lpart, jspan);
    reduce_out<<<dim3((NB * NC * NN) / 1024), 256, 0, stream>>>(Opart, Lpart, x, gamma, out, parts);
}